// Round 4
// baseline (2805.798 us; speedup 1.0000x reference)
//
#include <hip/hip_runtime.h>
#include <math.h>

// NestedOscillator two-pass bitwise-exact scan — 2-dep-chain step.
//
// Step reformulation (bitwise equal to np.mod reference, proven + verified
// absmax 0.0 through R1-R3):
//  - wrap decision via precomputed exact threshold T: fl(x+d) >= 2pi <=> x >= T
//    (fl(x+d) is monotone in x; T found by bounded ulp-walk at kernel start).
//    This moves cmp+select OFF the critical chain: step = (x + d) - amt,
//    amt in {0, 2pi} selected in parallel with the add.
//  - amt=2pi case: Sterbenz-exact subtract == fmod (ts in [2pi, 4pi)).
//    amt=0 case: ts - 0.0f == ts bitwise (all values >= +0).
//  - crossed(t) == slow_{t-1} wrapped == (slow_{t-1} >= T), computed a step
//    early, off-chain.
//  - reset: nf*k (k=0.5) < 2pi -> reference mod is identity. Pass1 guards the
//    rare mul (~800/100k) with a wave-uniform __any branch (1 active lane) so
//    it stays off the 99.2% chain; pass2 uses branchless *m (nf*1.0f == nf).
//  - omega = (float)exp((double)log_omega) == numpy f32 exp (verified R1-R3).

#define TWO_PI_F 6.28318530717958647692f
#define K_STEPS  25

// Exact min x with fl(x+d) >= TWO_PI_F. Monotone predicate -> ulp-walk is exact.
__device__ __forceinline__ float wrap_threshold(float d)
{
    float x = TWO_PI_F - d;  // within a few ulp of the true boundary
    for (int i = 0; i < 256 && (x + d >= TWO_PI_F); ++i)
        x = __uint_as_float(__float_as_uint(x) - 1u);   // walk down while true
    for (int i = 0; i < 256 && (x + d < TWO_PI_F); ++i)
        x = __uint_as_float(__float_as_uint(x) + 1u);   // first true from below
    return x;
}

__global__ __launch_bounds__(64, 1)
void osc_pass1(const float* __restrict__ lsw, const float* __restrict__ lfw,
               const float* __restrict__ rs, float4* __restrict__ snap,
               int nchunk)
{
    if (threadIdx.x != 0) return;
    const float ws = (float)exp((double)lsw[0]);
    const float wfq = (float)exp((double)lfw[0]);
    const float k  = 1.0f - rs[0];
    const float ds = ws * 0.001f;
    const float df = wfq * 0.001f;
    const float Ts = wrap_threshold(ds);
    const float Tf = wrap_threshold(df);

    float slow = 0.0f, fast = 0.0f;
    bool wrap = false;                    // t=0: prev=0 -> no crossing

    for (int c = 0; c < nchunk; ++c) {
        snap[c] = make_float4(slow, fast, wrap ? 1.0f : 0.0f, 0.0f);
#pragma unroll
        for (int i = 0; i < K_STEPS; ++i) {
            const bool crossed = wrap;
            const bool wsb = (slow >= Ts);            // off-chain, parallel
            const bool wfb = (fast >= Tf);
            const float amt_s = wsb ? TWO_PI_F : 0.0f;
            const float amt_f = wfb ? TWO_PI_F : 0.0f;
            slow = (slow + ds) - amt_s;               // 2-dep chain
            float nf = (fast + df) - amt_f;
            if (__any((int)crossed))                  // wave-uniform: lane 0 only
                nf = nf * k;                          // rare (~0.8% of steps)
            fast = nf;
            wrap = wsb;
        }
    }
}

__global__ __launch_bounds__(256)
void osc_pass2(const float* __restrict__ lsw, const float* __restrict__ lfw,
               const float* __restrict__ rs, const float4* __restrict__ snap,
               float* __restrict__ out, int steps, int nchunk)
{
    const int c = blockIdx.x * blockDim.x + threadIdx.x;
    if (c >= nchunk) return;

    const float ws = (float)exp((double)lsw[0]);
    const float wfq = (float)exp((double)lfw[0]);
    const float k  = 1.0f - rs[0];
    const float ds = ws * 0.001f;
    const float df = wfq * 0.001f;
    const float Ts = wrap_threshold(ds);
    const float Tf = wrap_threshold(df);
    const float inv2pi = 0.15915494309189533577f;

    float4 s = snap[c];
    float slow = s.x, fast = s.y;
    bool wrap = (s.z != 0.0f);

    float* __restrict__ o_slow = out;
    float* __restrict__ o_fast = out + steps;
    float* __restrict__ o_fis  = out + 2 * steps;
    const int base = c * K_STEPS;

#pragma unroll 5
    for (int i = 0; i < K_STEPS; ++i) {
        const int t = base + i;
        o_slow[t] = slow;
        o_fast[t] = fast;
        o_fis[t]  = slow * inv2pi;
        // bitwise-identical step, branchless (many divergent lanes here)
        const bool crossed = wrap;
        const bool wsb = (slow >= Ts);
        const bool wfb = (fast >= Tf);
        const float amt_s = wsb ? TWO_PI_F : 0.0f;
        const float amt_f = wfb ? TWO_PI_F : 0.0f;
        const float m = crossed ? k : 1.0f;
        slow = (slow + ds) - amt_s;
        fast = ((fast + df) - amt_f) * m;             // *1.0f is bit-exact
        wrap = wsb;
    }
}

extern "C" void kernel_launch(void* const* d_in, const int* in_sizes, int n_in,
                              void* d_out, int out_size, void* d_ws, size_t ws_size,
                              hipStream_t stream)
{
    const float* lsw = (const float*)d_in[0];
    const float* lfw = (const float*)d_in[1];
    const float* rs  = (const float*)d_in[2];
    float* out = (float*)d_out;
    const int steps  = out_size / 3;                     // 100000
    const int nchunk = (steps + K_STEPS - 1) / K_STEPS;  // 4000

    float4* snap = (float4*)d_ws;                        // 4000 * 16B = 64 KB

    hipLaunchKernelGGL(osc_pass1, dim3(1), dim3(64), 0, stream,
                       lsw, lfw, rs, snap, nchunk);
    const int threads = 256;
    const int blocks = (nchunk + threads - 1) / threads;
    hipLaunchKernelGGL(osc_pass2, dim3(blocks), dim3(threads), 0, stream,
                       lsw, lfw, rs, snap, out, steps, nchunk);
}